// Round 9
// baseline (3089.880 us; speedup 1.0000x reference)
//
#include <hip/hip_runtime.h>

#pragma clang fp contract(off)

typedef unsigned long long u64;
typedef unsigned int u32;

#define ALPHA  0.9f
#define RHO    0.985f
#define BETA_A 1.8f
#define TH     1.0f
#define CAP    (1 << 24)

// ---------------------------------------------------------------------------
// Generic 32x32 tiled transpose: src[R][C] -> dst[C][R]
// ---------------------------------------------------------------------------
__global__ __launch_bounds__(256) void transpose_k(const float* __restrict__ src,
                                                   float* __restrict__ dst,
                                                   int R, int C) {
    __shared__ float tile[32][33];
    const int c0 = blockIdx.x * 32;
    const int r0 = blockIdx.y * 32;
    const int tx = threadIdx.x, ty = threadIdx.y;
#pragma unroll
    for (int i = 0; i < 4; ++i)
        tile[ty + i * 8][tx] = src[(r0 + ty + i * 8) * C + c0 + tx];
    __syncthreads();
#pragma unroll
    for (int i = 0; i < 4; ++i)
        dst[(c0 + ty + i * 8) * R + r0 + tx] = tile[tx][ty + i * 8];
}

// ---------------------------------------------------------------------------
// Input projection: out[r][n] = sum_k inp[r][k] * Wt[k][n] + bias[n]
// ---------------------------------------------------------------------------
__global__ __launch_bounds__(256) void ip_gemm(const float* __restrict__ inp,
                                               const float* __restrict__ Wt,
                                               const float* __restrict__ bias,
                                               float* __restrict__ out) {
    __shared__ __align__(16) float s_in[512 * 20];
    const int tid   = threadIdx.x;
    const int chunk = blockIdx.x;
    const int rbase = blockIdx.y * 16;

    for (int idx = tid; idx < 16 * 512; idx += 256) {
        const int r = idx >> 9, k = idx & 511;
        s_in[k * 20 + r] = inp[(rbase + r) * 512 + k];
    }
    __syncthreads();

    const int n = chunk * 256 + tid;
    float acc[16];
#pragma unroll
    for (int r = 0; r < 16; ++r) acc[r] = 0.f;

    for (int k = 0; k < 512; ++k) {
        const float w = Wt[k * 1024 + n];
        const float4* p = (const float4*)(s_in + k * 20);
        const float4 x0 = p[0], x1 = p[1], x2 = p[2], x3 = p[3];
        acc[0]  = fmaf(x0.x, w, acc[0]);  acc[1]  = fmaf(x0.y, w, acc[1]);
        acc[2]  = fmaf(x0.z, w, acc[2]);  acc[3]  = fmaf(x0.w, w, acc[3]);
        acc[4]  = fmaf(x1.x, w, acc[4]);  acc[5]  = fmaf(x1.y, w, acc[5]);
        acc[6]  = fmaf(x1.z, w, acc[6]);  acc[7]  = fmaf(x1.w, w, acc[7]);
        acc[8]  = fmaf(x2.x, w, acc[8]);  acc[9]  = fmaf(x2.y, w, acc[9]);
        acc[10] = fmaf(x2.z, w, acc[10]); acc[11] = fmaf(x2.w, w, acc[11]);
        acc[12] = fmaf(x3.x, w, acc[12]); acc[13] = fmaf(x3.y, w, acc[13]);
        acc[14] = fmaf(x3.z, w, acc[14]); acc[15] = fmaf(x3.w, w, acc[15]);
    }
    const float bn = bias[n];
#pragma unroll
    for (int r = 0; r < 16; ++r) out[(rbase + r) * 1024 + n] = acc[r] + bn;
}

// ---------------------------------------------------------------------------
__device__ __forceinline__ u64 ld_u64(const u64* p) {
    return __hip_atomic_load(p, __ATOMIC_RELAXED, __HIP_MEMORY_SCOPE_AGENT);
}
__device__ __forceinline__ void st_u64(u64* p, u64 v) {
    __hip_atomic_store(p, v, __ATOMIC_RELAXED, __HIP_MEMORY_SCOPE_AGENT);
}
__device__ __forceinline__ u64 ld_lds(const u64* p) {
    return __hip_atomic_load(p, __ATOMIC_RELAXED, __HIP_MEMORY_SCOPE_WORKGROUP);
}
__device__ __forceinline__ void st_lds(u64* p, u64 v) {
    __hip_atomic_store(p, v, __ATOMIC_RELAXED, __HIP_MEMORY_SCOPE_WORKGROUP);
}

// index-based gather for out_gemm
__device__ __forceinline__ float gather_idx(const float* __restrict__ W,
                                            const int* __restrict__ list, int cnt, int col) {
    float a0 = 0.f, a1 = 0.f, a2 = 0.f, a3 = 0.f;
    int i = 0;
    for (; i + 4 <= cnt; i += 4) {
        const int4 j = *(const int4*)(list + i);
        a0 += W[j.x * 256 + col];
        a1 += W[j.y * 256 + col];
        a2 += W[j.z * 256 + col];
        a3 += W[j.w * 256 + col];
    }
    for (; i < cnt; ++i) a0 += W[list[i] * 256 + col];
    return (a0 + a1) + (a2 + a3);
}

// ---------------------------------------------------------------------------
// Fully asynchronous main kernel: 256 blocks x 512 threads, NO barriers and
// NO comm waves in the main loop. Each wave owns (batch b, 64 cols) and is an
// independent agent: publish epoch-tagged ((e<<32)|bits32) u64 words to LDS
// (own-block consumers) + global lines (3 partner slice-blocks); gather =
// poll 32 tagged words in fixed order, ctz-walk bits, accumulate directly
// (no lists). Wave-level drift hides exchange RTT: a spinning wave leaves its
// SIMD to the other resident waves. Spins are CAP-bounded; no barrier ->
// no deadlock. Word order 0..31 + ctz order = deterministic summation.
// Buffer safety: publishing ty0(e+2) requires having consumed all ty1(e+1)
// words, which transitively implies all readers consumed epoch e (same
// parity) -- the par double-buffer is race-free.
// bid=g*8+x: slice s=x>>1 (cols [s*256,+256), XCD-pinned, L2-resident
// weights); pair p=g*2+(x&1); wave wid: bi=wid>>2 (batch 2p+bi), q=wid&3
// (col quarter). Word w in [0,32) covers rows [w*32, w*32+32).
// ---------------------------------------------------------------------------
__global__ __launch_bounds__(512) void rsnn_async(
    const float* __restrict__ Wt_pre,   // [1536][1024]
    const float* __restrict__ Wt_ad,    // [1024][1024]
    const float* __restrict__ Wt_post,  // [1536][1024]
    const float* __restrict__ IP_pre,   // [4096][1024]
    const float* __restrict__ IP_post,  // [4096][1024]
    const float* __restrict__ b_ad_p,   // [1024]
    u64* __restrict__ lines,            // [128 b][2 par][2 ty][32 words]
    u64* __restrict__ spkO,             // [4096][16]
    float* __restrict__ out)
{
    const int tid  = threadIdx.x;
    const int bid  = blockIdx.x;
    const int x    = bid & 7;
    const int g    = bid >> 3;
    const int s    = x >> 1;
    const int p    = g * 2 + (x & 1);
    const int wid  = tid >> 6;
    const int lane = tid & 63;
    const int bi   = wid >> 2;
    const int q    = wid & 3;
    const int b    = 2 * p + bi;
    const int col  = s * 256 + q * 64 + lane;
    const int colB = col * 4;
    const u64 M32  = 0xffffffffull;

    __shared__ u64 ltag[2][2][2][8];   // [bi][par][ty][slot = q*2+h]
    if (tid < 64) ((u64*)ltag)[tid] = 0;
    __syncthreads();                   // only barrier: LDS tag init

    const char* WadB    = (const char*)Wt_ad;
    const char* WpreAB  = (const char*)(Wt_pre  + 512 * 1024);
    const char* WpostAB = (const char*)(Wt_post + 512 * 1024);

    float v_pre = 0.f, v_a = 0.f, ba = 0.f, v_post = 0.f, accA = 0.f;
    bool  sa = false;
    const float bad = b_ad_p[col];
    float ipre = 0.f, ipost = 0.f;

    for (int e = 1; e <= 96; ++e) {
        const int par = e & 1;
        const u64 tag = ((u64)e) << 32;
        if ((e - 1) % 3 == 0) {
            const int t = (e - 1) / 3;
            ipre  = IP_pre [(t * 128 + b) * 1024 + col];
            ipost = IP_post[(t * 128 + b) * 1024 + col];
        }
        u64* gl0 = lines + ((b * 2 + par) * 2 + 0) * 32;
        u64* gl1 = lines + ((b * 2 + par) * 2 + 1) * 32;

        // ---------------- A: v_pre update, publish s_pre -----------------
        v_pre = ALPHA * v_pre + ipre + accA;
        float d = v_pre - TH;
        const bool sp = d > 0.f;
        if (sp) v_pre = d;
        {
            const u64 m = __ballot(sp);
            if (lane == 0) {
                st_u64(&gl0[s * 8 + q * 2],     tag | (m & M32));
                st_u64(&gl0[s * 8 + q * 2 + 1], tag | (m >> 32));
                st_lds(&ltag[bi][par][0][q * 2],     tag | (m & M32));
                st_lds(&ltag[bi][par][0][q * 2 + 1], tag | (m >> 32));
            }
        }

        // ---------------- B: poll+walk s_pre words, v_a update ------------
        float accB = 0.f;
        for (int w = 0; w < 32; ++w) {
            u64 v;
            if ((w >> 3) == s) {
                const u64* lp = &ltag[bi][par][0][w & 7];
                int gd = 0;
                do { v = ld_lds(lp); } while ((v >> 32) != (u64)e && ++gd < CAP);
            } else {
                int gd = 0;
                do { v = ld_u64(&gl0[w]); } while ((v >> 32) != (u64)e && ++gd < CAP);
            }
            u32 bits = (u32)v;
            const u32 base = ((u32)w) << 17;   // w*32 rows * 4096 B/row
            while (bits) {
                const int bt = __builtin_ctz(bits);
                bits &= bits - 1;
                accB += *(const float*)(WadB + (base + (((u32)bt) << 12) + (u32)colB));
            }
        }
        v_a = ALPHA * v_a + accB + bad;
        const float th = TH + BETA_A * ba;
        d = v_a - th;
        sa = d > 0.f;
        if (sa) v_a = d;
        ba = RHO * ba + (sa ? 1.f : 0.f);
        {
            const u64 m = __ballot(sa);
            if (lane == 0) {
                st_u64(&gl1[s * 8 + q * 2],     tag | (m & M32));
                st_u64(&gl1[s * 8 + q * 2 + 1], tag | (m >> 32));
                st_lds(&ltag[bi][par][1][q * 2],     tag | (m & M32));
                st_lds(&ltag[bi][par][1][q * 2 + 1], tag | (m >> 32));
            }
        }

        // -------- C + next-A: poll+walk s_a words (2 loads per spike) -----
        float accC = 0.f;
        accA = 0.f;
        for (int w = 0; w < 32; ++w) {
            u64 v;
            if ((w >> 3) == s) {
                const u64* lp = &ltag[bi][par][1][w & 7];
                int gd = 0;
                do { v = ld_lds(lp); } while ((v >> 32) != (u64)e && ++gd < CAP);
            } else {
                int gd = 0;
                do { v = ld_u64(&gl1[w]); } while ((v >> 32) != (u64)e && ++gd < CAP);
            }
            u32 bits = (u32)v;
            const u32 base = ((u32)w) << 17;
            while (bits) {
                const int bt = __builtin_ctz(bits);
                bits &= bits - 1;
                const u32 off = base + (((u32)bt) << 12) + (u32)colB;
                accC += *(const float*)(WpostAB + off);
                accA += *(const float*)(WpreAB  + off);
            }
        }

        // ---------------- C: v_post update, outputs ----------------------
        v_post = ALPHA * v_post + ipost + accC;
        d = v_post - TH;
        const bool spost = d > 0.f;
        if (spost) v_post = d;
        if (e % 3 == 0) {                       // k == 2 of timestep t
            const u64 m = __ballot(spost);
            if (lane == 0)
                st_u64(&spkO[(((e - 1) / 3) * 128 + b) * 16 + s * 4 + q], m);
        }
        if (e == 96)
            out[32 * 128 * 256 + b * 1024 + col] = sa ? 1.f : 0.f;
    }
}

// ---------------------------------------------------------------------------
// Final output GEMM: o[r] = s_post[r] @ W_out.T + b_out, from spkO bitmaps.
// ---------------------------------------------------------------------------
__global__ __launch_bounds__(256) void out_gemm(const float* __restrict__ Wt_out,
                                                const float* __restrict__ b_out,
                                                const u64* __restrict__ spkO,
                                                float* __restrict__ out) {
    __shared__ u64 bmp[16];
    __shared__ int pc[16];
    __shared__ __align__(16) int list[1024];
    const int r = blockIdx.x, tid = threadIdx.x;
    if (tid < 16) {
        const u64 m = ld_u64(&spkO[r * 16 + tid]);
        bmp[tid] = m;
        pc[tid]  = __popcll(m);
    }
    __syncthreads();
    int total = 0;
#pragma unroll
    for (int w = 0; w < 16; ++w) total += pc[w];
    for (int j = tid; j < 1024; j += 256) {
        const int w = j >> 6, bit = j & 63;
        const u64 m = bmp[w];
        if ((m >> bit) & 1ull) {
            int base = __popcll(m & ((1ull << bit) - 1ull));
            for (int q2 = 0; q2 < w; ++q2) base += pc[q2];
            list[base] = j;
        }
    }
    __syncthreads();
    const float acc = gather_idx(Wt_out, list, total, tid);
    out[r * 256 + tid] = acc + b_out[tid];
}

// ---------------------------------------------------------------------------
extern "C" void kernel_launch(void* const* d_in, const int* in_sizes, int n_in,
                              void* d_out, int out_size, void* d_ws, size_t ws_size,
                              hipStream_t stream) {
    (void)in_sizes; (void)n_in; (void)out_size; (void)ws_size;
    const float* inp    = (const float*)d_in[0];
    const float* W_pre  = (const float*)d_in[1];
    const float* b_pre  = (const float*)d_in[2];
    const float* W_ad   = (const float*)d_in[3];
    const float* b_ad   = (const float*)d_in[4];
    const float* W_post = (const float*)d_in[5];
    const float* b_post = (const float*)d_in[6];
    const float* W_out  = (const float*)d_in[7];
    const float* b_out  = (const float*)d_in[8];

    char* base = (char*)d_ws;
    u64*  lines = (u64*)(base + 4096);               // 128 KB exchange lines
    u64*  spkO  = (u64*)(base + 4096 + 131072);      // 512 KB
    float* ws      = (float*)(base + 1048576);
    float* Wt_pre  = ws;
    float* Wt_post = Wt_pre  + 1536 * 1024;
    float* Wt_ad   = Wt_post + 1536 * 1024;
    float* Wt_out  = Wt_ad   + 1024 * 1024;
    float* IP_pre  = Wt_out  + 1024 * 256;
    float* IP_post = IP_pre  + 4096 * 1024;

    hipMemsetAsync(base, 0, 4096 + 131072, stream);  // zero exchange lines

    transpose_k<<<dim3(48, 32), dim3(32, 8), 0, stream>>>(W_pre,  Wt_pre,  1024, 1536);
    transpose_k<<<dim3(48, 32), dim3(32, 8), 0, stream>>>(W_post, Wt_post, 1024, 1536);
    transpose_k<<<dim3(32, 32), dim3(32, 8), 0, stream>>>(W_ad,   Wt_ad,   1024, 1024);
    transpose_k<<<dim3(32, 8),  dim3(32, 8), 0, stream>>>(W_out,  Wt_out,  256,  1024);

    ip_gemm<<<dim3(4, 256), 256, 0, stream>>>(inp, Wt_pre,  b_pre,  IP_pre);
    ip_gemm<<<dim3(4, 256), 256, 0, stream>>>(inp, Wt_post, b_post, IP_post);

    rsnn_async<<<256, 512, 0, stream>>>(Wt_pre, Wt_ad, Wt_post,
                                        IP_pre, IP_post, b_ad,
                                        lines, spkO, (float*)d_out);

    out_gemm<<<4096, 256, 0, stream>>>(Wt_out, b_out, spkO, (float*)d_out);
}

// Round 10
// 1067.387 us; speedup vs baseline: 2.8948x; 2.8948x over previous
//
#include <hip/hip_runtime.h>

#pragma clang fp contract(off)

typedef unsigned long long u64;
typedef unsigned int u32;

#define ALPHA  0.9f
#define RHO    0.985f
#define BETA_A 1.8f
#define TH     1.0f
#define CAP    (1 << 24)

// ---------------------------------------------------------------------------
// Generic 32x32 tiled transpose: src[R][C] -> dst[C][R]
// ---------------------------------------------------------------------------
__global__ __launch_bounds__(256) void transpose_k(const float* __restrict__ src,
                                                   float* __restrict__ dst,
                                                   int R, int C) {
    __shared__ float tile[32][33];
    const int c0 = blockIdx.x * 32;
    const int r0 = blockIdx.y * 32;
    const int tx = threadIdx.x, ty = threadIdx.y;
#pragma unroll
    for (int i = 0; i < 4; ++i)
        tile[ty + i * 8][tx] = src[(r0 + ty + i * 8) * C + c0 + tx];
    __syncthreads();
#pragma unroll
    for (int i = 0; i < 4; ++i)
        dst[(c0 + ty + i * 8) * R + r0 + tx] = tile[tx][ty + i * 8];
}

// ---------------------------------------------------------------------------
// Merged input projection: both IP_pre and IP_post from one s_in staging.
// ---------------------------------------------------------------------------
__global__ __launch_bounds__(256) void ip_gemm2(const float* __restrict__ inp,
                                                const float* __restrict__ Wt_a,
                                                const float* __restrict__ bias_a,
                                                float* __restrict__ out_a,
                                                const float* __restrict__ Wt_b,
                                                const float* __restrict__ bias_b,
                                                float* __restrict__ out_b) {
    __shared__ __align__(16) float s_in[512 * 20];
    const int tid   = threadIdx.x;
    const int chunk = blockIdx.x;
    const int rbase = blockIdx.y * 16;

    for (int idx = tid; idx < 16 * 512; idx += 256) {
        const int r = idx >> 9, k = idx & 511;
        s_in[k * 20 + r] = inp[(rbase + r) * 512 + k];
    }
    __syncthreads();

    const int n = chunk * 256 + tid;
    float acca[16], accb[16];
#pragma unroll
    for (int r = 0; r < 16; ++r) { acca[r] = 0.f; accb[r] = 0.f; }

    for (int k = 0; k < 512; ++k) {
        const float wa = Wt_a[k * 1024 + n];
        const float wb = Wt_b[k * 1024 + n];
        const float4* p = (const float4*)(s_in + k * 20);
        const float4 x0 = p[0], x1 = p[1], x2 = p[2], x3 = p[3];
        acca[0]  = fmaf(x0.x, wa, acca[0]);  accb[0]  = fmaf(x0.x, wb, accb[0]);
        acca[1]  = fmaf(x0.y, wa, acca[1]);  accb[1]  = fmaf(x0.y, wb, accb[1]);
        acca[2]  = fmaf(x0.z, wa, acca[2]);  accb[2]  = fmaf(x0.z, wb, accb[2]);
        acca[3]  = fmaf(x0.w, wa, acca[3]);  accb[3]  = fmaf(x0.w, wb, accb[3]);
        acca[4]  = fmaf(x1.x, wa, acca[4]);  accb[4]  = fmaf(x1.x, wb, accb[4]);
        acca[5]  = fmaf(x1.y, wa, acca[5]);  accb[5]  = fmaf(x1.y, wb, accb[5]);
        acca[6]  = fmaf(x1.z, wa, acca[6]);  accb[6]  = fmaf(x1.z, wb, accb[6]);
        acca[7]  = fmaf(x1.w, wa, acca[7]);  accb[7]  = fmaf(x1.w, wb, accb[7]);
        acca[8]  = fmaf(x2.x, wa, acca[8]);  accb[8]  = fmaf(x2.x, wb, accb[8]);
        acca[9]  = fmaf(x2.y, wa, acca[9]);  accb[9]  = fmaf(x2.y, wb, accb[9]);
        acca[10] = fmaf(x2.z, wa, acca[10]); accb[10] = fmaf(x2.z, wb, accb[10]);
        acca[11] = fmaf(x2.w, wa, acca[11]); accb[11] = fmaf(x2.w, wb, accb[11]);
        acca[12] = fmaf(x3.x, wa, acca[12]); accb[12] = fmaf(x3.x, wb, accb[12]);
        acca[13] = fmaf(x3.y, wa, acca[13]); accb[13] = fmaf(x3.y, wb, accb[13]);
        acca[14] = fmaf(x3.z, wa, acca[14]); accb[14] = fmaf(x3.z, wb, accb[14]);
        acca[15] = fmaf(x3.w, wa, acca[15]); accb[15] = fmaf(x3.w, wb, accb[15]);
    }
    const float bna = bias_a[n];
    const float bnb = bias_b[n];
#pragma unroll
    for (int r = 0; r < 16; ++r) {
        out_a[(rbase + r) * 1024 + n] = acca[r] + bna;
        out_b[(rbase + r) * 1024 + n] = accb[r] + bnb;
    }
}

// ---------------------------------------------------------------------------
__device__ __forceinline__ u64 ld_u64(const u64* p) {
    return __hip_atomic_load(p, __ATOMIC_RELAXED, __HIP_MEMORY_SCOPE_AGENT);
}
__device__ __forceinline__ void st_u64(u64* p, u64 v) {
    __hip_atomic_store(p, v, __ATOMIC_RELAXED, __HIP_MEMORY_SCOPE_AGENT);
}
__device__ __forceinline__ u64 ld_lds(const u64* p) {
    return __hip_atomic_load(p, __ATOMIC_RELAXED, __HIP_MEMORY_SCOPE_WORKGROUP);
}
__device__ __forceinline__ void st_lds(u64* p, u64 v) {
    __hip_atomic_store(p, v, __ATOMIC_RELAXED, __HIP_MEMORY_SCOPE_WORKGROUP);
}
__device__ __forceinline__ int ld_seq(const int* p) {       // acquire (LDS)
    return __hip_atomic_load(p, __ATOMIC_ACQUIRE, __HIP_MEMORY_SCOPE_WORKGROUP);
}
__device__ __forceinline__ void st_seq(int* p, int v) {     // release (LDS)
    __hip_atomic_store(p, v, __ATOMIC_RELEASE, __HIP_MEMORY_SCOPE_WORKGROUP);
}

// Gather over byte-offset list segment [i0, i1): 4-accumulator, int4 steps.
__device__ __forceinline__ float gatherseg(const char* __restrict__ Wb,
                                           const int* __restrict__ list,
                                           int i0, int i1, int colB) {
    float a0 = 0.f, a1 = 0.f, a2 = 0.f, a3 = 0.f;
    int i = i0;
    for (; i + 4 <= i1; i += 4) {
        const int4 j = *(const int4*)(list + i);
        a0 += *(const float*)(Wb + (u32)(j.x + colB));
        a1 += *(const float*)(Wb + (u32)(j.y + colB));
        a2 += *(const float*)(Wb + (u32)(j.z + colB));
        a3 += *(const float*)(Wb + (u32)(j.w + colB));
    }
    for (; i < i1; ++i) a0 += *(const float*)(Wb + (u32)(list[i] + colB));
    return (a0 + a1) + (a2 + a3);
}

// Fused two-matrix gather over one list (C uses Wpost rows, next-A uses Wpre).
__device__ __forceinline__ void gather2seg(const char* __restrict__ Wc,
                                           const char* __restrict__ Wa,
                                           const int* __restrict__ list,
                                           int cnt, int colB,
                                           float& accC, float& accA) {
    float c0 = 0.f, c1 = 0.f, c2 = 0.f, c3 = 0.f;
    float a0 = 0.f, a1 = 0.f, a2 = 0.f, a3 = 0.f;
    int i = 0;
    for (; i + 4 <= cnt; i += 4) {
        const int4 j = *(const int4*)(list + i);
        c0 += *(const float*)(Wc + (u32)(j.x + colB));
        a0 += *(const float*)(Wa + (u32)(j.x + colB));
        c1 += *(const float*)(Wc + (u32)(j.y + colB));
        a1 += *(const float*)(Wa + (u32)(j.y + colB));
        c2 += *(const float*)(Wc + (u32)(j.z + colB));
        a2 += *(const float*)(Wa + (u32)(j.z + colB));
        c3 += *(const float*)(Wc + (u32)(j.w + colB));
        a3 += *(const float*)(Wa + (u32)(j.w + colB));
    }
    for (; i < cnt; ++i) {
        const u32 off = (u32)(list[i] + colB);
        c0 += *(const float*)(Wc + off);
        a0 += *(const float*)(Wa + off);
    }
    accC = (c0 + c1) + (c2 + c3);
    accA = (a0 + a1) + (a2 + a3);
}

// index-based gather for out_gemm
__device__ __forceinline__ float gather_idx(const float* __restrict__ W,
                                            const int* __restrict__ list, int cnt, int col) {
    float a0 = 0.f, a1 = 0.f, a2 = 0.f, a3 = 0.f;
    int i = 0;
    for (; i + 4 <= cnt; i += 4) {
        const int4 j = *(const int4*)(list + i);
        a0 += W[j.x * 256 + col];
        a1 += W[j.y * 256 + col];
        a2 += W[j.z * 256 + col];
        a3 += W[j.w * 256 + col];
    }
    for (; i < cnt; ++i) a0 += W[list[i] * 256 + col];
    return (a0 + a1) + (a2 + a3);
}

// ---------------------------------------------------------------------------
// Barrier-free producer-consumer kernel: 256 blocks x 640 threads.
// r7's engine (comm waves: parallel 32-word poll + prefix-scan list build;
// compute waves: int4 list gathers; slices XCD-pinned) with every in-loop
// __syncthreads replaced by per-batch LDS sequence flags:
//   comm wave bi: poll ty0(e) -> build listP[bi] -> cntP[bi] -> seqP[bi]=e
//                 (release); then ty1(e) -> listS[bi] -> seqS[bi]=e.
//   compute wave (bi,q): publish ballot (global lines + LDS ltag) -> spin
//                 seqP[bi]>=e (acquire, ~60cy LDS reads) -> gather -> ...
// The two batches drift independently; no vmcnt(0) barrier drains; spinning
// waves yield SIMD issue slots to gathering waves. No barriers -> no deadlock;
// spins CAP'd. List build order = word 0..31, ctz within word (deterministic).
// Buffer safety: wave publishes ty0(e+2)[same parity as e] only after passing
// seqS(e+1), which requires its comm wave to have read partner ty1(e+1) words,
// which partners publish only after their B(e)/C(e) completed -> every reader
// of epoch-e lines has consumed them. Tags ((e<<32)|bits32) self-validate.
// ---------------------------------------------------------------------------
__global__ __launch_bounds__(640) void rsnn_nb(
    const float* __restrict__ Wt_pre,   // [1536][1024]
    const float* __restrict__ Wt_ad,    // [1024][1024]
    const float* __restrict__ Wt_post,  // [1536][1024]
    const float* __restrict__ IP_pre,   // [4096][1024]
    const float* __restrict__ IP_post,  // [4096][1024]
    const float* __restrict__ b_ad_p,   // [1024]
    u64* __restrict__ lines,            // [128 b][2 par][2 ty][32 words]
    u64* __restrict__ spkO,             // [4096][16]
    float* __restrict__ out)
{
    const int tid  = threadIdx.x;
    const int bid  = blockIdx.x;
    const int x    = bid & 7;
    const int g    = bid >> 3;
    const int s    = x >> 1;
    const int p    = g * 2 + (x & 1);
    const int wid  = tid >> 6;
    const int lane = tid & 63;
    const u64 M32  = 0xffffffffull;

    __shared__ __align__(16) int listP[2][1024];
    __shared__ __align__(16) int listS[2][1024];
    __shared__ u64 ltag[2][2][2][8];   // [bi][par][ty][word-in-slice]
    __shared__ int seqP[2], seqS[2], cntP[2], cntS[2];

    if (tid < 64) ((u64*)ltag)[tid] = 0;
    if (tid < 2) { seqP[tid] = 0; seqS[tid] = 0; }
    __syncthreads();                   // init-only barrier

    const char* WadB    = (const char*)Wt_ad;
    const char* WpreAB  = (const char*)(Wt_pre  + 512 * 1024);
    const char* WpostAB = (const char*)(Wt_post + 512 * 1024);

    if (wid < 8) {
        // ============================ compute ============================
        const int bi   = wid >> 2;
        const int q    = wid & 3;
        const int b    = 2 * p + bi;
        const int col  = s * 256 + q * 64 + lane;
        const int colB = col * 4;

        float v_pre = 0.f, v_a = 0.f, ba = 0.f, v_post = 0.f, accA = 0.f;
        bool  sa = false;
        const float bad = b_ad_p[col];
        float ipre = 0.f, ipost = 0.f;

        for (int e = 1; e <= 96; ++e) {
            const int par = e & 1;
            const u64 tag = ((u64)e) << 32;
            if ((e - 1) % 3 == 0) {
                const int t = (e - 1) / 3;
                ipre  = IP_pre [(t * 128 + b) * 1024 + col];
                ipost = IP_post[(t * 128 + b) * 1024 + col];
            }
            u64* gl0 = lines + ((b * 2 + par) * 2 + 0) * 32;
            u64* gl1 = lines + ((b * 2 + par) * 2 + 1) * 32;

            // ---- A: v_pre update, publish s_pre ----
            v_pre = ALPHA * v_pre + ipre + accA;
            float d = v_pre - TH;
            const bool sp = d > 0.f;
            if (sp) v_pre = d;
            {
                const u64 m = __ballot(sp);
                if (lane == 0) {
                    st_u64(&gl0[s * 8 + 2 * q],     tag | (m & M32));
                    st_u64(&gl0[s * 8 + 2 * q + 1], tag | (m >> 32));
                    st_lds(&ltag[bi][par][0][2 * q],     tag | (m & M32));
                    st_lds(&ltag[bi][par][0][2 * q + 1], tag | (m >> 32));
                }
            }
            // ---- wait listP (LDS spin), B gather, v_a update ----
            {
                int gd = 0;
                while (ld_seq(&seqP[bi]) < e && ++gd < CAP) {}
            }
            const float accB = gatherseg(WadB, listP[bi], 0, cntP[bi], colB);
            v_a = ALPHA * v_a + accB + bad;
            const float th = TH + BETA_A * ba;
            d = v_a - th;
            sa = d > 0.f;
            if (sa) v_a = d;
            ba = RHO * ba + (sa ? 1.f : 0.f);
            {
                const u64 m = __ballot(sa);
                if (lane == 0) {
                    st_u64(&gl1[s * 8 + 2 * q],     tag | (m & M32));
                    st_u64(&gl1[s * 8 + 2 * q + 1], tag | (m >> 32));
                    st_lds(&ltag[bi][par][1][2 * q],     tag | (m & M32));
                    st_lds(&ltag[bi][par][1][2 * q + 1], tag | (m >> 32));
                }
            }
            // ---- wait listS, fused C + next-A gather, v_post update ----
            {
                int gd = 0;
                while (ld_seq(&seqS[bi]) < e && ++gd < CAP) {}
            }
            float accC;
            gather2seg(WpostAB, WpreAB, listS[bi], cntS[bi], colB, accC, accA);
            v_post = ALPHA * v_post + ipost + accC;
            d = v_post - TH;
            const bool spost = d > 0.f;
            if (spost) v_post = d;
            if (e % 3 == 0) {                       // k == 2 of timestep t
                const u64 m = __ballot(spost);
                if (lane == 0)
                    st_u64(&spkO[(((e - 1) / 3) * 128 + b) * 16 + s * 4 + q], m);
            }
            if (e == 96)
                out[32 * 128 * 256 + b * 1024 + col] = sa ? 1.f : 0.f;
        }
    } else {
        // ================== comm wave per batch (wid 8,9) =================
        const int bi = wid - 8;
        const int b  = 2 * p + bi;
        const bool act = lane < 32;
        const int sl = lane >> 3, h = lane & 7;    // word = sl*8+h
        const int jbase = (sl * 256 + h * 32) << 12;

        for (int e = 1; e <= 96; ++e) {
            const int par = e & 1;
            const u64* gl0 = lines + ((b * 2 + par) * 2 + 0) * 32;
            const u64* gl1 = lines + ((b * 2 + par) * 2 + 1) * 32;

            // ---- ty0 -> listP[bi] ----
            u32 bits = 0;
            if (act) {
                u64 v; int gd = 0;
                if (sl == s) {
                    do { v = ld_lds(&ltag[bi][par][0][h]); }
                    while ((v >> 32) != (u64)e && ++gd < CAP);
                } else {
                    do { v = ld_u64(&gl0[lane]); }
                    while ((v >> 32) != (u64)e && ++gd < CAP);
                }
                bits = (u32)v;
            }
            {
                const int pc = __popc(bits);
                int incl = pc;
#pragma unroll
                for (int dlt = 1; dlt < 32; dlt <<= 1) {
                    const int v = __shfl_up(incl, dlt, 64);
                    if (lane >= dlt && lane < 32) incl += v;
                }
                int base = incl - pc;
                u32 m = bits;
                while (m) {
                    const int bt = __builtin_ctz(m);
                    m &= m - 1;
                    listP[bi][base++] = jbase + (bt << 12);
                }
                if (lane == 31) { cntP[bi] = incl; st_seq(&seqP[bi], e); }
            }

            // ---- ty1 -> listS[bi] ----
            bits = 0;
            if (act) {
                u64 v; int gd = 0;
                if (sl == s) {
                    do { v = ld_lds(&ltag[bi][par][1][h]); }
                    while ((v >> 32) != (u64)e && ++gd < CAP);
                } else {
                    do { v = ld_u64(&gl1[lane]); }
                    while ((v >> 32) != (u64)e && ++gd < CAP);
                }
                bits = (u32)v;
            }
            {
                const int pc = __popc(bits);
                int incl = pc;
#pragma unroll
                for (int dlt = 1; dlt < 32; dlt <<= 1) {
                    const int v = __shfl_up(incl, dlt, 64);
                    if (lane >= dlt && lane < 32) incl += v;
                }
                int base = incl - pc;
                u32 m = bits;
                while (m) {
                    const int bt = __builtin_ctz(m);
                    m &= m - 1;
                    listS[bi][base++] = jbase + (bt << 12);
                }
                if (lane == 31) { cntS[bi] = incl; st_seq(&seqS[bi], e); }
            }
        }
    }
}

// ---------------------------------------------------------------------------
// Final output GEMM: o[r] = s_post[r] @ W_out.T + b_out, from spkO bitmaps.
// ---------------------------------------------------------------------------
__global__ __launch_bounds__(256) void out_gemm(const float* __restrict__ Wt_out,
                                                const float* __restrict__ b_out,
                                                const u64* __restrict__ spkO,
                                                float* __restrict__ out) {
    __shared__ u64 bmp[16];
    __shared__ int pc[16];
    __shared__ __align__(16) int list[1024];
    const int r = blockIdx.x, tid = threadIdx.x;
    if (tid < 16) {
        const u64 m = ld_u64(&spkO[r * 16 + tid]);
        bmp[tid] = m;
        pc[tid]  = __popcll(m);
    }
    __syncthreads();
    int total = 0;
#pragma unroll
    for (int w = 0; w < 16; ++w) total += pc[w];
    for (int j = tid; j < 1024; j += 256) {
        const int w = j >> 6, bit = j & 63;
        const u64 m = bmp[w];
        if ((m >> bit) & 1ull) {
            int base = __popcll(m & ((1ull << bit) - 1ull));
            for (int q2 = 0; q2 < w; ++q2) base += pc[q2];
            list[base] = j;
        }
    }
    __syncthreads();
    const float acc = gather_idx(Wt_out, list, total, tid);
    out[r * 256 + tid] = acc + b_out[tid];
}

// ---------------------------------------------------------------------------
extern "C" void kernel_launch(void* const* d_in, const int* in_sizes, int n_in,
                              void* d_out, int out_size, void* d_ws, size_t ws_size,
                              hipStream_t stream) {
    (void)in_sizes; (void)n_in; (void)out_size; (void)ws_size;
    const float* inp    = (const float*)d_in[0];
    const float* W_pre  = (const float*)d_in[1];
    const float* b_pre  = (const float*)d_in[2];
    const float* W_ad   = (const float*)d_in[3];
    const float* b_ad   = (const float*)d_in[4];
    const float* W_post = (const float*)d_in[5];
    const float* b_post = (const float*)d_in[6];
    const float* W_out  = (const float*)d_in[7];
    const float* b_out  = (const float*)d_in[8];

    char* base = (char*)d_ws;
    u64*  lines = (u64*)(base + 4096);               // 128 KB exchange lines
    u64*  spkO  = (u64*)(base + 4096 + 131072);      // 512 KB
    float* ws      = (float*)(base + 1048576);
    float* Wt_pre  = ws;
    float* Wt_post = Wt_pre  + 1536 * 1024;
    float* Wt_ad   = Wt_post + 1536 * 1024;
    float* Wt_out  = Wt_ad   + 1024 * 1024;
    float* IP_pre  = Wt_out  + 1024 * 256;
    float* IP_post = IP_pre  + 4096 * 1024;

    hipMemsetAsync(base, 0, 4096 + 131072, stream);  // zero exchange lines

    transpose_k<<<dim3(48, 32), dim3(32, 8), 0, stream>>>(W_pre,  Wt_pre,  1024, 1536);
    transpose_k<<<dim3(48, 32), dim3(32, 8), 0, stream>>>(W_post, Wt_post, 1024, 1536);
    transpose_k<<<dim3(32, 32), dim3(32, 8), 0, stream>>>(W_ad,   Wt_ad,   1024, 1024);
    transpose_k<<<dim3(32, 8),  dim3(32, 8), 0, stream>>>(W_out,  Wt_out,  256,  1024);

    ip_gemm2<<<dim3(4, 256), 256, 0, stream>>>(inp, Wt_pre, b_pre, IP_pre,
                                               Wt_post, b_post, IP_post);

    rsnn_nb<<<256, 640, 0, stream>>>(Wt_pre, Wt_ad, Wt_post,
                                     IP_pre, IP_post, b_ad,
                                     lines, spkO, (float*)d_out);

    out_gemm<<<4096, 256, 0, stream>>>(Wt_out, b_out, spkO, (float*)d_out);
}